// Round 13
// baseline (1210.212 us; speedup 1.0000x reference)
//
#include <hip/hip_runtime.h>
#include <math.h>

#define SS 4096
#define EE 1024
#define HH 16
#define DD 64
#define RMAX 128
#define NCOL 128
#define NTR  8
#define NRED 8
#define NPROJ 1536
#define NBG 64
#define RSPLIT 4
#define REP 16   // instrumentation: x16 idempotent repeat so each kernel shows in top-5

// ---------------------------------------------------------------------------
// INSTRUMENTATION ROUND: identical algorithm/layout to round 12; every kernel
// body repeated REP times (idempotent re-writes, memory clobber between reps)
// so per-kernel durations appear in rocprof top-5. Real time = shown / REP.
// ---------------------------------------------------------------------------
#define OFF_SUMX  64
#define OFF_BGA   1088
#define OFF_BETA  2112
#define OFF_ALPHA 6208
#define OFF_PART  8192
#define OFF_XT    (OFF_PART + EE * NCOL)
#define OFF_QH    (OFF_XT + EE * RMAX)
#define OFF_KTH   (OFF_QH + HH * RMAX * DD)
#define OFF_VH    (OFF_KTH + HH * DD * RMAX)

__device__ __forceinline__ void seg_scan(const int* __restrict__ seg,
                                         const int* __restrict__ posp,
                                         int* sh, int& s0, int& L) {
    if (threadIdx.x == 0) { sh[0] = SS; sh[1] = -1; }
    __syncthreads();
    int sid = seg[posp[0]];
    int lmin = SS, lmax = -1;
    for (int i = threadIdx.x; i < SS; i += 256)
        if (seg[i] == sid) { lmin = min(lmin, i); lmax = max(lmax, i); }
#pragma unroll
    for (int off = 32; off; off >>= 1) {
        lmin = min(lmin, __shfl_xor(lmin, off));
        lmax = max(lmax, __shfl_xor(lmax, off));
    }
    if ((threadIdx.x & 63) == 0) { atomicMin(&sh[0], lmin); atomicMax(&sh[1], lmax); }
    __syncthreads();
    s0 = sh[0];
    L  = sh[1] - sh[0] + 1;
    if (L > RMAX) L = RMAX;
    if (L < 1)    L = 1;
}

// -------- D0: colsum -> partT (128 blk) || x-seg transpose -> xT (8 blk) ----
__global__ __launch_bounds__(256) void d0_kernel(
    const float* __restrict__ x, const int* __restrict__ seg,
    const int* __restrict__ posp, float* __restrict__ ws) {
    int bid = blockIdx.x, tid = threadIdx.x;
    if (bid < NCOL) {
        float* partT = ws + OFF_PART;
        int r0 = bid * (SS / NCOL);
        const float4* x4 = (const float4*)x;
        for (int rep = 0; rep < REP; ++rep) {
            float4 a = make_float4(0.f, 0.f, 0.f, 0.f);
#pragma unroll 8
            for (int r = 0; r < SS / NCOL; ++r) {
                float4 v = x4[(size_t)(r0 + r) * 256 + tid];
                a.x += v.x; a.y += v.y; a.z += v.z; a.w += v.w;
            }
            partT[(size_t)(4 * tid + 0) * NCOL + bid] = a.x;
            partT[(size_t)(4 * tid + 1) * NCOL + bid] = a.y;
            partT[(size_t)(4 * tid + 2) * NCOL + bid] = a.z;
            partT[(size_t)(4 * tid + 3) * NCOL + bid] = a.w;
            asm volatile("" ::: "memory");
        }
        return;
    }
    __shared__ float t[128 * 129];
    __shared__ int sh[2];
    int s0, L;
    seg_scan(seg, posp, sh, s0, L);
    int kb = bid - NCOL;
    if (kb == 0 && tid == 0) { ((int*)ws)[0] = s0; ((int*)ws)[1] = L; }
    int k0 = kb * 128;
    float* xT = ws + OFF_XT;
    for (int rep = 0; rep < REP; ++rep) {
        for (int idx = tid; idx < 128 * 32; idx += 256) {
            int r = idx >> 5, c4 = idx & 31;
            float4 v = make_float4(0.f, 0.f, 0.f, 0.f);
            if (r < L) v = *(const float4*)(x + (size_t)(s0 + r) * EE + k0 + c4 * 4);
            t[r * 129 + c4 * 4 + 0] = v.x;
            t[r * 129 + c4 * 4 + 1] = v.y;
            t[r * 129 + c4 * 4 + 2] = v.z;
            t[r * 129 + c4 * 4 + 3] = v.w;
        }
        __syncthreads();
        for (int idx = tid; idx < 128 * 32; idx += 256) {
            int k = idx >> 5, r4 = idx & 31;
            float4 o;
            o.x = t[(r4 * 4 + 0) * 129 + k];
            o.y = t[(r4 * 4 + 1) * 129 + k];
            o.z = t[(r4 * 4 + 2) * 129 + k];
            o.w = t[(r4 * 4 + 3) * 129 + k];
            *(float4*)(xT + (size_t)(k0 + k) * RMAX + r4 * 4) = o;
        }
        __syncthreads();
        asm volatile("" ::: "memory");
    }
}

// -------- D1: sumx reduce (8 blk) || QKV projection (1536 blk) --------
__global__ __launch_bounds__(256) void d1_kernel(
    const float* __restrict__ Wq, const float* __restrict__ bq,
    const float* __restrict__ Wk, const float* __restrict__ bk,
    const float* __restrict__ Wv, const float* __restrict__ bv,
    float* __restrict__ ws) {
    int bid = blockIdx.x, tid = threadIdx.x;
    if (bid < NRED) {
        const float* partT = ws + OFF_PART;
        int e  = bid * 128 + (tid >> 1);
        int c0 = (tid & 1) * 64;
        for (int rep = 0; rep < REP; ++rep) {
            const float4* p4 = (const float4*)(partT + (size_t)e * NCOL + c0);
            float4 s4 = make_float4(0.f, 0.f, 0.f, 0.f);
#pragma unroll
            for (int i = 0; i < 16; ++i) {
                float4 v = p4[i];
                s4.x += v.x; s4.y += v.y; s4.z += v.z; s4.w += v.w;
            }
            float s = s4.x + s4.y + s4.z + s4.w;
            s += __shfl_xor(s, 1);
            if ((tid & 1) == 0) (ws + OFF_SUMX)[e] = s;
            asm volatile("" ::: "memory");
        }
        return;
    }
    __shared__ float red[16 * 66];
    int L  = ((const int*)ws)[1];
    int Lp = (L + 63) & ~63;
    int pid = bid - NRED;
    int m   = pid / 512;
    int rem = pid - m * 512;
    int eb  = rem >> 1;
    int rt  = rem & 1;
    int r0  = rt * 64;
    if (r0 >= Lp) return;
    int e0 = eb * 4;
    const float* W = (m == 0) ? Wq : ((m == 1) ? Wk : Wv);
    const float* b = (m == 0) ? bq : ((m == 1) ? bk : bv);
    int lane = tid & 63;
    int w4 = __builtin_amdgcn_readfirstlane(tid >> 6);
    const float* xcol = ws + OFF_XT + r0 + lane;
    int kbase = w4 * 256;
    const float* wr0 = W + (size_t)e0 * EE + kbase;
    float* qh  = ws + OFF_QH;
    float* kTh = ws + OFF_KTH;
    float* vh  = ws + OFF_VH;
    for (int rep = 0; rep < REP; ++rep) {
        float acc0 = 0.f, acc1 = 0.f, acc2 = 0.f, acc3 = 0.f;
        float xv0[8], xv1[8];
#pragma unroll
        for (int u = 0; u < 8; ++u) xv0[u] = xcol[(size_t)(kbase + u) * RMAX];
        for (int kk = 0; kk < 256; kk += 16) {
#pragma unroll
            for (int u = 0; u < 8; ++u)
                xv1[u] = xcol[(size_t)(kbase + kk + 8 + u) * RMAX];
#pragma unroll
            for (int u = 0; u < 8; ++u) {
                float w0 = wr0[0 * EE + kk + u];
                float w1 = wr0[1 * EE + kk + u];
                float w2 = wr0[2 * EE + kk + u];
                float w3 = wr0[3 * EE + kk + u];
                acc0 += xv0[u] * w0; acc1 += xv0[u] * w1;
                acc2 += xv0[u] * w2; acc3 += xv0[u] * w3;
            }
#pragma unroll
            for (int u = 0; u < 8; ++u)
                xv0[u] = xcol[(size_t)(kbase + kk + 16 + u) * RMAX];
#pragma unroll
            for (int u = 0; u < 8; ++u) {
                float w0 = wr0[0 * EE + kk + 8 + u];
                float w1 = wr0[1 * EE + kk + 8 + u];
                float w2 = wr0[2 * EE + kk + 8 + u];
                float w3 = wr0[3 * EE + kk + 8 + u];
                acc0 += xv1[u] * w0; acc1 += xv1[u] * w1;
                acc2 += xv1[u] * w2; acc3 += xv1[u] * w3;
            }
        }
        red[(w4 * 4 + 0) * 66 + lane] = acc0;
        red[(w4 * 4 + 1) * 66 + lane] = acc1;
        red[(w4 * 4 + 2) * 66 + lane] = acc2;
        red[(w4 * 4 + 3) * 66 + lane] = acc3;
        __syncthreads();
        int p  = tid >> 6;
        int rg = r0 + lane;
        int h = e0 >> 6, d0 = (e0 & 63) + p;
        float v = 0.f;
        if (rg < L)
            v = red[(0 * 4 + p) * 66 + lane] + red[(1 * 4 + p) * 66 + lane]
              + red[(2 * 4 + p) * 66 + lane] + red[(3 * 4 + p) * 66 + lane]
              + b[e0 + p];
        if (m == 1) kTh[(size_t)(h * DD + d0) * RMAX + rg] = v;
        else        ((m == 0) ? qh : vh)[((size_t)h * RMAX + rg) * DD + d0] = v;
        __syncthreads();
        asm volatile("" ::: "memory");
    }
}

// -------- D2: bgA GEMV (64 blk) || attention beta/alpha (64 blk) --------
__global__ __launch_bounds__(256) void d2_kernel(
    const float* __restrict__ Wv, const float* __restrict__ bv,
    float* __restrict__ ws) {
    __shared__ float kT[64 * 128];
    __shared__ float vS[128 * 64];
    __shared__ float sc[4 * 128];
    __shared__ float vsum[64];
    __shared__ float mwp[4][64];
    __shared__ float awp[4];
    const float* sumx = ws + OFF_SUMX;
    float* bgA    = ws + OFF_BGA;
    float* betap  = ws + OFF_BETA;
    float* alphap = ws + OFF_ALPHA;
    const float* qh  = ws + OFF_QH;
    const float* kTh = ws + OFF_KTH;
    const float* vh  = ws + OFF_VH;

    int bid = blockIdx.x, tid = threadIdx.x;
    int lane = tid & 63, wave = tid >> 6;
    int L  = ((const int*)ws)[1];
    int Lp = (L + 63) & ~63;
    int nt = Lp >> 6;

    if (bid < NBG) {
        int e = bid * 16 + (tid >> 4);
        int j = tid & 15;
        for (int rep = 0; rep < REP; ++rep) {
            const float4* wr  = (const float4*)(Wv + (size_t)e * EE);
            const float4* sx4 = (const float4*)sumx;
            float p = 0.f;
#pragma unroll
            for (int jj = 0; jj < 16; ++jj) {
                float4 w = wr[jj * 16 + j], z = sx4[jj * 16 + j];
                p += w.x * z.x + w.y * z.y + w.z * z.z + w.w * z.w;
            }
            p += __shfl_xor(p, 8);
            p += __shfl_xor(p, 4);
            p += __shfl_xor(p, 2);
            p += __shfl_xor(p, 1);
            if (j == 0) bgA[e] = p + (float)SS * bv[e];
            asm volatile("" ::: "memory");
        }
        return;
    }

    int aid = bid - NBG;
    int h   = aid / RSPLIT;
    int q4  = aid % RSPLIT;

    for (int rep = 0; rep < REP; ++rep) {
        {
            const float4* src = (const float4*)(kTh + (size_t)h * DD * RMAX);
            float4* dst = (float4*)kT;
            for (int i = tid; i < 64 * 128 / 4; i += 256) dst[i] = src[i];
            const float4* src2 = (const float4*)(vh + (size_t)h * RMAX * DD);
            float4* dst2 = (float4*)vS;
            for (int i = tid; i < 128 * 64 / 4; i += 256) dst2[i] = src2[i];
        }
        __syncthreads();
        {
            int d = tid >> 2, q = tid & 3;
            float s = 0.f;
            for (int t = q; t < Lp; t += 4) s += vS[t * 64 + d];
            s += __shfl_xor(s, 1);
            s += __shfl_xor(s, 2);
            if (q == 0) vsum[d] = s;
        }
        __syncthreads();

        float bw = 0.f, aw = 0.f;
        int rpb = Lp / RSPLIT;
        int rlo = q4 * rpb;
        int rhi = rlo + rpb; if (rhi > L) rhi = L;
        float* scw = sc + wave * 128;
        for (int r = rlo + wave; r < rhi; r += 4) {
            float qreg = qh[((size_t)h * RMAX + r) * DD + lane];
            float mmax = 0.f;
            for (int c = 0; c < nt; ++c) {
                float s = 0.f;
                const float* kp = kT + c * 64 + lane;
#pragma unroll
                for (int d = 0; d < 64; ++d) s += __shfl(qreg, d) * kp[d * 128];
                scw[c * 64 + lane] = s;
                mmax = fmaxf(mmax, (c * 64 + lane) < L ? s : -3.0e38f);
            }
#pragma unroll
            for (int off = 32; off; off >>= 1) mmax = fmaxf(mmax, __shfl_xor(mmax, off));
            float Zl = 0.f;
            for (int c = 0; c < nt; ++c) {
                float w = ((c * 64 + lane) < L) ? __expf(scw[c * 64 + lane] - mmax) : 0.f;
                Zl += w;
                scw[c * 64 + lane] = w;
            }
#pragma unroll
            for (int off = 32; off; off >>= 1) Zl += __shfl_xor(Zl, off);
            float em = __expf(-mmax);
            float Z  = Zl + (float)(SS - L) * em;
            float acc = 0.f;
            for (int c = 0; c < nt; ++c) {
                const float* vp  = vS + c * 64 * 64 + lane;
                const float* scc = scw + c * 64;
#pragma unroll 16
                for (int tt = 0; tt < 64; ++tt) acc += scc[tt] * vp[tt * 64];
            }
            float invZ = 1.0f / Z;
            bw += acc * invZ;
            aw += em * invZ;
        }
        mwp[wave][lane] = bw;
        if (lane == 0) awp[wave] = aw;
        __syncthreads();
        if (tid < 64) {
            float asum = awp[0] + awp[1] + awp[2] + awp[3];
            float beta = mwp[0][tid] + mwp[1][tid] + mwp[2][tid] + mwp[3][tid]
                       - asum * vsum[tid];
            betap[aid * 64 + tid] = beta;
            if (tid == 0) alphap[aid] = asum;
        }
        __syncthreads();
        asm volatile("" ::: "memory");
    }
}

// -------- D3: out[e] = bo[e] + Wo[e,:].(beta~ + alpha o bgA) / L --------
__global__ __launch_bounds__(256) void d3_kernel(
    const float* __restrict__ Wo, const float* __restrict__ bo,
    const float* __restrict__ ws, float* __restrict__ out) {
    __shared__ float z[EE];
    const float* bgA    = ws + OFF_BGA;
    const float* betap  = ws + OFF_BETA;
    const float* alphap = ws + OFF_ALPHA;
    int tid = threadIdx.x;
    int lane = tid & 63, wave = tid >> 6;
    int L = ((const int*)ws)[1];

    for (int rep = 0; rep < REP; ++rep) {
        {
            int h = tid >> 4;
            const float4* bp4 = (const float4*)betap;
            float4 bsum = make_float4(0.f, 0.f, 0.f, 0.f);
            float  asum = 0.f;
#pragma unroll
            for (int q = 0; q < RSPLIT; ++q) {
                float4 v = bp4[(h * RSPLIT + q) * 16 + (tid & 15)];
                bsum.x += v.x; bsum.y += v.y; bsum.z += v.z; bsum.w += v.w;
                asum += alphap[h * RSPLIT + q];
            }
            float4 g = ((const float4*)bgA)[tid];
            ((float4*)z)[tid] = make_float4(bsum.x + asum * g.x, bsum.y + asum * g.y,
                                            bsum.z + asum * g.z, bsum.w + asum * g.w);
        }
        __syncthreads();

        int e = blockIdx.x * 4 + wave;
        const float4* wr = (const float4*)(Wo + (size_t)e * EE);
        const float4* z4 = (const float4*)z;
        float p = 0.f;
#pragma unroll
        for (int it = 0; it < 4; ++it) {
            float4 w = wr[it * 64 + lane], zz = z4[it * 64 + lane];
            p += w.x * zz.x + w.y * zz.y + w.z * zz.z + w.w * zz.w;
        }
#pragma unroll
        for (int off = 32; off; off >>= 1) p += __shfl_xor(p, off);
        if (lane == 0) out[e] = bo[e] + p / (float)L;
        __syncthreads();
        asm volatile("" ::: "memory");
    }
}

extern "C" void kernel_launch(void* const* d_in, const int* in_sizes, int n_in,
                              void* d_out, int out_size, void* d_ws, size_t ws_size,
                              hipStream_t stream) {
    const float* x   = (const float*)d_in[0];
    const float* Wq  = (const float*)d_in[1];
    const float* bq  = (const float*)d_in[2];
    const float* Wk  = (const float*)d_in[3];
    const float* bk  = (const float*)d_in[4];
    const float* Wv  = (const float*)d_in[5];
    const float* bv  = (const float*)d_in[6];
    const float* Wo  = (const float*)d_in[7];
    const float* bo  = (const float*)d_in[8];
    const int*   seg = (const int*)d_in[9];
    const int*   pos = (const int*)d_in[10];
    float*       out = (float*)d_out;
    float*       ws  = (float*)d_ws;

    d0_kernel<<<NCOL + NTR, 256, 0, stream>>>(x, seg, pos, ws);
    d1_kernel<<<NRED + NPROJ, 256, 0, stream>>>(Wq, bq, Wk, bk, Wv, bv, ws);
    d2_kernel<<<NBG + HH * RSPLIT, 256, 0, stream>>>(Wv, bv, ws);
    d3_kernel<<<EE / 4, 256, 0, stream>>>(Wo, bo, ws, out);
}

// Round 14
// 73.830 us; speedup vs baseline: 16.3919x; 16.3919x over previous
//
#include <hip/hip_runtime.h>
#include <math.h>

#define SS 4096
#define EE 1024
#define HH 16
#define DD 64
#define RMAX 128
#define NCOL 128
#define NTR  8
#define NRED 8
#define NPROJ 1536
#define NBG 64     // bgA GEMV blocks in D2
#define NVS 16     // vsumh blocks in D2
#define NATT 256   // attention blocks in D2 (1 per CU, 4 waves each)

// ---------------------------------------------------------------------------
// ws float offsets. LESSONS: (r9/r10) no 4KB-strided ws reads; (r3) no BULK
// global atomics (sparse ~100K low-contention atomics are fine, r4); (r5/r7)
// no software grid barriers; (r13, measured) d2's LDS-staging + shallow-flight
// loads ran at 6 GB/s — keep many independent unrolled loads in flight, one
// wave per work item, no global->LDS staging of L2-resident data.
//   meta   int[0..1]      (s0, L) written by D0
//   sumx   [EE]           @64
//   bgA    [EE]           @1088
//   betap  [HH][DD]       @2112   (atomic; zeroed by D1 block 0)
//   alphap [HH]           @3136   (atomic; zeroed by D1 block 0)
//   vsumh  [HH][DD]       @3200
//   partT  [EE][NCOL]     @8192
//   xT     [EE][RMAX]     @139264
//   qh     [HH][RMAX][DD] @270336
//   kTh    [HH][DD][RMAX] @401408
//   vh     [HH][RMAX][DD] @532480
// ---------------------------------------------------------------------------
#define OFF_SUMX  64
#define OFF_BGA   1088
#define OFF_BETA  2112
#define OFF_ALPHA 3136
#define OFF_VSUM  3200
#define OFF_PART  8192
#define OFF_XT    (OFF_PART + EE * NCOL)
#define OFF_QH    (OFF_XT + EE * RMAX)
#define OFF_KTH   (OFF_QH + HH * RMAX * DD)
#define OFF_VH    (OFF_KTH + HH * DD * RMAX)

__device__ __forceinline__ void seg_scan(const int* __restrict__ seg,
                                         const int* __restrict__ posp,
                                         int* sh, int& s0, int& L) {
    if (threadIdx.x == 0) { sh[0] = SS; sh[1] = -1; }
    __syncthreads();
    int sid = seg[posp[0]];
    int lmin = SS, lmax = -1;
    for (int i = threadIdx.x; i < SS; i += 256)
        if (seg[i] == sid) { lmin = min(lmin, i); lmax = max(lmax, i); }
#pragma unroll
    for (int off = 32; off; off >>= 1) {
        lmin = min(lmin, __shfl_xor(lmin, off));
        lmax = max(lmax, __shfl_xor(lmax, off));
    }
    if ((threadIdx.x & 63) == 0) { atomicMin(&sh[0], lmin); atomicMax(&sh[1], lmax); }
    __syncthreads();
    s0 = sh[0];
    L  = sh[1] - sh[0] + 1;
    if (L > RMAX) L = RMAX;
    if (L < 1)    L = 1;
}

// -------- D0: colsum -> partT (128 blk) || x-seg transpose -> xT (8 blk) ----
__global__ __launch_bounds__(256) void d0_kernel(
    const float* __restrict__ x, const int* __restrict__ seg,
    const int* __restrict__ posp, float* __restrict__ ws) {
    int bid = blockIdx.x, tid = threadIdx.x;
    if (bid < NCOL) {
        float* partT = ws + OFF_PART;
        int r0 = bid * (SS / NCOL);
        const float4* x4 = (const float4*)x;
        float4 a = make_float4(0.f, 0.f, 0.f, 0.f);
#pragma unroll 8
        for (int r = 0; r < SS / NCOL; ++r) {
            float4 v = x4[(size_t)(r0 + r) * 256 + tid];
            a.x += v.x; a.y += v.y; a.z += v.z; a.w += v.w;
        }
        partT[(size_t)(4 * tid + 0) * NCOL + bid] = a.x;
        partT[(size_t)(4 * tid + 1) * NCOL + bid] = a.y;
        partT[(size_t)(4 * tid + 2) * NCOL + bid] = a.z;
        partT[(size_t)(4 * tid + 3) * NCOL + bid] = a.w;
        return;
    }
    __shared__ float t[128 * 129];
    __shared__ int sh[2];
    int s0, L;
    seg_scan(seg, posp, sh, s0, L);
    int kb = bid - NCOL;
    if (kb == 0 && tid == 0) { ((int*)ws)[0] = s0; ((int*)ws)[1] = L; }
    int k0 = kb * 128;
    float* xT = ws + OFF_XT;
    for (int idx = tid; idx < 128 * 32; idx += 256) {
        int r = idx >> 5, c4 = idx & 31;
        float4 v = make_float4(0.f, 0.f, 0.f, 0.f);
        if (r < L) v = *(const float4*)(x + (size_t)(s0 + r) * EE + k0 + c4 * 4);
        t[r * 129 + c4 * 4 + 0] = v.x;
        t[r * 129 + c4 * 4 + 1] = v.y;
        t[r * 129 + c4 * 4 + 2] = v.z;
        t[r * 129 + c4 * 4 + 3] = v.w;
    }
    __syncthreads();
    for (int idx = tid; idx < 128 * 32; idx += 256) {
        int k = idx >> 5, r4 = idx & 31;
        float4 o;
        o.x = t[(r4 * 4 + 0) * 129 + k];
        o.y = t[(r4 * 4 + 1) * 129 + k];
        o.z = t[(r4 * 4 + 2) * 129 + k];
        o.w = t[(r4 * 4 + 3) * 129 + k];
        *(float4*)(xT + (size_t)(k0 + k) * RMAX + r4 * 4) = o;
    }
}

// -------- D1: sumx reduce + beta/alpha zero (8 blk) || QKV proj (1536 blk) ---
__global__ __launch_bounds__(256) void d1_kernel(
    const float* __restrict__ Wq, const float* __restrict__ bq,
    const float* __restrict__ Wk, const float* __restrict__ bk,
    const float* __restrict__ Wv, const float* __restrict__ bv,
    float* __restrict__ ws) {
    int bid = blockIdx.x, tid = threadIdx.x;
    if (bid < NRED) {
        if (bid == 0) {   // zero betap+alphap atomic accumulators (1040 floats)
            for (int i = tid; i < 1088; i += 256) (ws + OFF_BETA)[i] = 0.f;
        }
        const float* partT = ws + OFF_PART;
        int e  = bid * 128 + (tid >> 1);
        int c0 = (tid & 1) * 64;
        const float4* p4 = (const float4*)(partT + (size_t)e * NCOL + c0);
        float4 s4 = make_float4(0.f, 0.f, 0.f, 0.f);
#pragma unroll
        for (int i = 0; i < 16; ++i) {
            float4 v = p4[i];
            s4.x += v.x; s4.y += v.y; s4.z += v.z; s4.w += v.w;
        }
        float s = s4.x + s4.y + s4.z + s4.w;
        s += __shfl_xor(s, 1);
        if ((tid & 1) == 0) (ws + OFF_SUMX)[e] = s;
        return;
    }
    __shared__ float red[16 * 66];
    int L  = ((const int*)ws)[1];
    int Lp = (L + 63) & ~63;
    int pid = bid - NRED;
    int m   = pid / 512;
    int rem = pid - m * 512;
    int eb  = rem >> 1;
    int rt  = rem & 1;
    int r0  = rt * 64;
    if (r0 >= Lp) return;
    int e0 = eb * 4;
    const float* W = (m == 0) ? Wq : ((m == 1) ? Wk : Wv);
    const float* b = (m == 0) ? bq : ((m == 1) ? bk : bv);
    int lane = tid & 63;
    int w4 = __builtin_amdgcn_readfirstlane(tid >> 6);
    const float* xcol = ws + OFF_XT + r0 + lane;
    int kbase = w4 * 256;
    const float* wr0 = W + (size_t)e0 * EE + kbase;
    float acc0 = 0.f, acc1 = 0.f, acc2 = 0.f, acc3 = 0.f;
    float xv0[8], xv1[8];
#pragma unroll
    for (int u = 0; u < 8; ++u) xv0[u] = xcol[(size_t)(kbase + u) * RMAX];
    for (int kk = 0; kk < 256; kk += 16) {
#pragma unroll
        for (int u = 0; u < 8; ++u)
            xv1[u] = xcol[(size_t)(kbase + kk + 8 + u) * RMAX];
#pragma unroll
        for (int u = 0; u < 8; ++u) {
            float w0 = wr0[0 * EE + kk + u];
            float w1 = wr0[1 * EE + kk + u];
            float w2 = wr0[2 * EE + kk + u];
            float w3 = wr0[3 * EE + kk + u];
            acc0 += xv0[u] * w0; acc1 += xv0[u] * w1;
            acc2 += xv0[u] * w2; acc3 += xv0[u] * w3;
        }
#pragma unroll
        for (int u = 0; u < 8; ++u)
            xv0[u] = xcol[(size_t)(kbase + kk + 16 + u) * RMAX];
#pragma unroll
        for (int u = 0; u < 8; ++u) {
            float w0 = wr0[0 * EE + kk + 8 + u];
            float w1 = wr0[1 * EE + kk + 8 + u];
            float w2 = wr0[2 * EE + kk + 8 + u];
            float w3 = wr0[3 * EE + kk + 8 + u];
            acc0 += xv1[u] * w0; acc1 += xv1[u] * w1;
            acc2 += xv1[u] * w2; acc3 += xv1[u] * w3;
        }
    }
    red[(w4 * 4 + 0) * 66 + lane] = acc0;
    red[(w4 * 4 + 1) * 66 + lane] = acc1;
    red[(w4 * 4 + 2) * 66 + lane] = acc2;
    red[(w4 * 4 + 3) * 66 + lane] = acc3;
    __syncthreads();
    int p  = tid >> 6;
    int rg = r0 + lane;
    float* qh  = ws + OFF_QH;
    float* kTh = ws + OFF_KTH;
    float* vh  = ws + OFF_VH;
    int h = e0 >> 6, d0 = (e0 & 63) + p;
    float v = 0.f;
    if (rg < L)
        v = red[(0 * 4 + p) * 66 + lane] + red[(1 * 4 + p) * 66 + lane]
          + red[(2 * 4 + p) * 66 + lane] + red[(3 * 4 + p) * 66 + lane]
          + b[e0 + p];
    if (m == 1) kTh[(size_t)(h * DD + d0) * RMAX + rg] = v;
    else        ((m == 0) ? qh : vh)[((size_t)h * RMAX + rg) * DD + d0] = v;
}

// -------- D2: bgA (64) || vsumh (16) || attention, 1 wave per (r,h) (256) ----
__global__ __launch_bounds__(256) void d2_kernel(
    const float* __restrict__ Wv, const float* __restrict__ bv,
    float* __restrict__ ws) {
    __shared__ float qS[4 * 64];
    __shared__ float wS[4 * 128];
    __shared__ float vp_[4][64];
    const float* sumx = ws + OFF_SUMX;
    float* bgA    = ws + OFF_BGA;
    float* betap  = ws + OFF_BETA;
    float* alphap = ws + OFF_ALPHA;
    float* vsumh  = ws + OFF_VSUM;
    const float* qh  = ws + OFF_QH;
    const float* kTh = ws + OFF_KTH;
    const float* vh  = ws + OFF_VH;

    int bid = blockIdx.x, tid = threadIdx.x;
    int lane = tid & 63, wave = tid >> 6;
    int L  = ((const int*)ws)[1];
    int Lp = (L + 63) & ~63;

    if (bid < NBG) {
        // bgA[e] = S*bv[e] + Wv[e,:].sumx ; 16 e per block, 16 thr per e
        int e = bid * 16 + (tid >> 4);
        int j = tid & 15;
        const float4* wr  = (const float4*)(Wv + (size_t)e * EE);
        const float4* sx4 = (const float4*)sumx;
        float p = 0.f;
#pragma unroll
        for (int jj = 0; jj < 16; ++jj) {
            float4 w = wr[jj * 16 + j], z = sx4[jj * 16 + j];
            p += w.x * z.x + w.y * z.y + w.z * z.z + w.w * z.w;
        }
        p += __shfl_xor(p, 8);
        p += __shfl_xor(p, 4);
        p += __shfl_xor(p, 2);
        p += __shfl_xor(p, 1);
        if (j == 0) bgA[e] = p + (float)SS * bv[e];
        return;
    }
    if (bid < NBG + NVS) {
        // vsumh[h][d] = sum_{t<Lp} vh[h][t][d]  (rows >= L are zero)
        int h = bid - NBG;
        float s = 0.f;
        for (int t = wave; t < Lp; t += 4)
            s += vh[((size_t)h * RMAX + t) * DD + lane];
        vp_[wave][lane] = s;
        __syncthreads();
        if (wave == 0)
            vsumh[h * DD + lane] = vp_[0][lane] + vp_[1][lane]
                                 + vp_[2][lane] + vp_[3][lane];
        return;
    }

    // attention: wave wg handles (r = wg>>4, h = wg&15)
    int aid = bid - NBG - NVS;            // 0..255
    int gidbase = aid * 4 + wave;         // 0..1023
    int pairs = L * HH;
    float* qSw = qS + wave * 64;
    float* wSw = wS + wave * 128;
    for (int wg = gidbase; wg < pairs; wg += NATT * 4) {
        int h = wg & (HH - 1);
        int r = wg >> 4;
        // q row -> LDS (wave-private), broadcast-read below
        qSw[lane] = qh[((size_t)h * RMAX + r) * DD + lane];
        // QK: lane = t (two 64-chunks); 128 independent coalesced L2 loads
        float s0 = 0.f, s1 = 0.f;
#pragma unroll
        for (int d = 0; d < 64; ++d) {
            float qd = qSw[d];                              // LDS broadcast
            const float* kr = kTh + (size_t)(h * DD + d) * RMAX;
            s0 += qd * kr[lane];
            s1 += qd * kr[64 + lane];
        }
        // softmax over the row (zero background participates in max)
        float v0 = (lane < L)      ? s0 : -3.0e38f;
        float v1 = (64 + lane < L) ? s1 : -3.0e38f;
        float m = fmaxf(0.f, fmaxf(v0, v1));
#pragma unroll
        for (int off = 32; off; off >>= 1) m = fmaxf(m, __shfl_xor(m, off));
        float w0 = (lane < L)      ? __expf(s0 - m) : 0.f;
        float w1 = (64 + lane < L) ? __expf(s1 - m) : 0.f;
        float Zl = w0 + w1;
#pragma unroll
        for (int off = 32; off; off >>= 1) Zl += __shfl_xor(Zl, off);
        float em = __expf(-m);
        float Z  = Zl + (float)(SS - L) * em;
        // PV: lane = d; weights broadcast from LDS, V coalesced from L2
        wSw[lane]      = w0;
        wSw[64 + lane] = w1;
        float acc = 0.f;
#pragma unroll 16
        for (int t = 0; t < Lp; ++t)
            acc += wSw[t] * vh[((size_t)h * RMAX + t) * DD + lane];
        float invZ = 1.0f / Z;
        atomicAdd(&betap[h * DD + lane], acc * invZ);
        if (lane == 0) atomicAdd(&alphap[h], em * invZ);
    }
}

// -------- D3: out[e] = bo[e] + Wo[e,:].(beta + alpha o (bgA - vsumh)) / L ----
__global__ __launch_bounds__(256) void d3_kernel(
    const float* __restrict__ Wo, const float* __restrict__ bo,
    const float* __restrict__ ws, float* __restrict__ out) {
    __shared__ float z[EE];
    int tid = threadIdx.x;
    int lane = tid & 63, wave = tid >> 6;
    int L = ((const int*)ws)[1];

    {
        int h = tid >> 4;
        float4 beta = ((const float4*)(ws + OFF_BETA))[tid];
        float  a    = (ws + OFF_ALPHA)[h];
        float4 g    = ((const float4*)(ws + OFF_BGA))[tid];
        float4 vs   = ((const float4*)(ws + OFF_VSUM))[tid];
        ((float4*)z)[tid] = make_float4(beta.x + a * (g.x - vs.x),
                                        beta.y + a * (g.y - vs.y),
                                        beta.z + a * (g.z - vs.z),
                                        beta.w + a * (g.w - vs.w));
    }
    __syncthreads();

    int e = blockIdx.x * 4 + wave;
    const float4* wr = (const float4*)(Wo + (size_t)e * EE);
    const float4* z4 = (const float4*)z;
    float p = 0.f;
#pragma unroll
    for (int it = 0; it < 4; ++it) {
        float4 w = wr[it * 64 + lane], zz = z4[it * 64 + lane];
        p += w.x * zz.x + w.y * zz.y + w.z * zz.z + w.w * zz.w;
    }
#pragma unroll
    for (int off = 32; off; off >>= 1) p += __shfl_xor(p, off);
    if (lane == 0) out[e] = bo[e] + p / (float)L;
}

extern "C" void kernel_launch(void* const* d_in, const int* in_sizes, int n_in,
                              void* d_out, int out_size, void* d_ws, size_t ws_size,
                              hipStream_t stream) {
    const float* x   = (const float*)d_in[0];
    const float* Wq  = (const float*)d_in[1];
    const float* bq  = (const float*)d_in[2];
    const float* Wk  = (const float*)d_in[3];
    const float* bk  = (const float*)d_in[4];
    const float* Wv  = (const float*)d_in[5];
    const float* bv  = (const float*)d_in[6];
    const float* Wo  = (const float*)d_in[7];
    const float* bo  = (const float*)d_in[8];
    const int*   seg = (const int*)d_in[9];
    const int*   pos = (const int*)d_in[10];
    float*       out = (float*)d_out;
    float*       ws  = (float*)d_ws;

    d0_kernel<<<NCOL + NTR, 256, 0, stream>>>(x, seg, pos, ws);
    d1_kernel<<<NRED + NPROJ, 256, 0, stream>>>(Wq, bq, Wk, bk, Wv, bv, ws);
    d2_kernel<<<NBG + NVS + NATT, 256, 0, stream>>>(Wv, bv, ws);
    d3_kernel<<<EE / 4, 256, 0, stream>>>(Wo, bo, ws, out);
}

// Round 15
// 71.565 us; speedup vs baseline: 16.9106x; 1.0316x over previous
//
#include <hip/hip_runtime.h>
#include <math.h>

#define SS 4096
#define EE 1024
#define HH 16
#define DD 64
#define RMAX 128
#define NCOL 128
#define NTR  8
#define NRED 8
#define NPROJ 768  // 3 m * 256 e-tiles(4e); W read exactly once
#define NBG 64     // bgA GEMV blocks in D2
#define NVS 16     // vsumh blocks in D2
#define NATT 256   // attention blocks in D2 (1 per CU, 4 waves each)

// ---------------------------------------------------------------------------
// ws float offsets. LESSONS: (r9/r10) no 4KB-strided ws reads; (r3) no BULK
// global atomics; (r5/r7) no software grid barriers; (r13) no shallow-flight
// staging loops (6 GB/s); (r14, measured) wave-uniform SCALAR loads of cold W
// stream at only 700 GB/s and the r-tile split double-fetched W — stream W
// ONCE via coalesced per-lane float4 into LDS, broadcast-read from LDS.
//   meta   int[0..1]      (s0, L) written by D0
//   sumx   [EE]           @64
//   bgA    [EE]           @1088
//   betap  [HH][DD]       @2112   (atomic; zeroed by D1 block 0)
//   alphap [HH]           @3136   (atomic; zeroed by D1 block 0)
//   vsumh  [HH][DD]       @3200
//   partT  [EE][NCOL]     @8192
//   xT     [EE][RMAX]     @139264 (zero-padded rows r>=L)
//   qh     [HH][RMAX][DD] @270336 (rows L..Lp-1 zeroed; rows >= Lp stale)
//   kTh    [HH][DD][RMAX] @401408
//   vh     [HH][RMAX][DD] @532480
// ---------------------------------------------------------------------------
#define OFF_SUMX  64
#define OFF_BGA   1088
#define OFF_BETA  2112
#define OFF_ALPHA 3136
#define OFF_VSUM  3200
#define OFF_PART  8192
#define OFF_XT    (OFF_PART + EE * NCOL)
#define OFF_QH    (OFF_XT + EE * RMAX)
#define OFF_KTH   (OFF_QH + HH * RMAX * DD)
#define OFF_VH    (OFF_KTH + HH * DD * RMAX)

__device__ __forceinline__ void seg_scan(const int* __restrict__ seg,
                                         const int* __restrict__ posp,
                                         int* sh, int& s0, int& L) {
    if (threadIdx.x == 0) { sh[0] = SS; sh[1] = -1; }
    __syncthreads();
    int sid = seg[posp[0]];
    int lmin = SS, lmax = -1;
    for (int i = threadIdx.x; i < SS; i += 256)
        if (seg[i] == sid) { lmin = min(lmin, i); lmax = max(lmax, i); }
#pragma unroll
    for (int off = 32; off; off >>= 1) {
        lmin = min(lmin, __shfl_xor(lmin, off));
        lmax = max(lmax, __shfl_xor(lmax, off));
    }
    if ((threadIdx.x & 63) == 0) { atomicMin(&sh[0], lmin); atomicMax(&sh[1], lmax); }
    __syncthreads();
    s0 = sh[0];
    L  = sh[1] - sh[0] + 1;
    if (L > RMAX) L = RMAX;
    if (L < 1)    L = 1;
}

// -------- D0: colsum -> partT (128 blk) || x-seg transpose -> xT (8 blk) ----
__global__ __launch_bounds__(256) void d0_kernel(
    const float* __restrict__ x, const int* __restrict__ seg,
    const int* __restrict__ posp, float* __restrict__ ws) {
    int bid = blockIdx.x, tid = threadIdx.x;
    if (bid < NCOL) {
        float* partT = ws + OFF_PART;
        int r0 = bid * (SS / NCOL);
        const float4* x4 = (const float4*)x;
        float4 a = make_float4(0.f, 0.f, 0.f, 0.f);
#pragma unroll 8
        for (int r = 0; r < SS / NCOL; ++r) {
            float4 v = x4[(size_t)(r0 + r) * 256 + tid];
            a.x += v.x; a.y += v.y; a.z += v.z; a.w += v.w;
        }
        partT[(size_t)(4 * tid + 0) * NCOL + bid] = a.x;
        partT[(size_t)(4 * tid + 1) * NCOL + bid] = a.y;
        partT[(size_t)(4 * tid + 2) * NCOL + bid] = a.z;
        partT[(size_t)(4 * tid + 3) * NCOL + bid] = a.w;
        return;
    }
    __shared__ float t[128 * 129];
    __shared__ int sh[2];
    int s0, L;
    seg_scan(seg, posp, sh, s0, L);
    int kb = bid - NCOL;
    if (kb == 0 && tid == 0) { ((int*)ws)[0] = s0; ((int*)ws)[1] = L; }
    int k0 = kb * 128;
    float* xT = ws + OFF_XT;
    for (int idx = tid; idx < 128 * 32; idx += 256) {
        int r = idx >> 5, c4 = idx & 31;
        float4 v = make_float4(0.f, 0.f, 0.f, 0.f);
        if (r < L) v = *(const float4*)(x + (size_t)(s0 + r) * EE + k0 + c4 * 4);
        t[r * 129 + c4 * 4 + 0] = v.x;
        t[r * 129 + c4 * 4 + 1] = v.y;
        t[r * 129 + c4 * 4 + 2] = v.z;
        t[r * 129 + c4 * 4 + 3] = v.w;
    }
    __syncthreads();
    for (int idx = tid; idx < 128 * 32; idx += 256) {
        int k = idx >> 5, r4 = idx & 31;
        float4 o;
        o.x = t[(r4 * 4 + 0) * 129 + k];
        o.y = t[(r4 * 4 + 1) * 129 + k];
        o.z = t[(r4 * 4 + 2) * 129 + k];
        o.w = t[(r4 * 4 + 3) * 129 + k];
        *(float4*)(xT + (size_t)(k0 + k) * RMAX + r4 * 4) = o;
    }
}

// -------- D1: sumx reduce + zero accum (8 blk) || QKV proj (768 blk) --------
// proj: block = 4 W rows x full K. W staged to LDS via coalesced float4
// vector loads (read ONCE); compute: lane = row, 4 waves split K 4x256,
// both 64-row halves per lane (half 2 skipped when Lp==64); W broadcast
// from LDS as float4; x columns register-prefetched from L2-resident xT.
__global__ __launch_bounds__(256) void d1_kernel(
    const float* __restrict__ Wq, const float* __restrict__ bq,
    const float* __restrict__ Wk, const float* __restrict__ bk,
    const float* __restrict__ Wv, const float* __restrict__ bv,
    float* __restrict__ ws) {
    int bid = blockIdx.x, tid = threadIdx.x;
    if (bid < NRED) {
        if (bid == 0) {   // zero betap+alphap atomic accumulators
            for (int i = tid; i < 1088; i += 256) (ws + OFF_BETA)[i] = 0.f;
        }
        const float* partT = ws + OFF_PART;
        int e  = bid * 128 + (tid >> 1);
        int c0 = (tid & 1) * 64;
        const float4* p4 = (const float4*)(partT + (size_t)e * NCOL + c0);
        float4 s4 = make_float4(0.f, 0.f, 0.f, 0.f);
#pragma unroll
        for (int i = 0; i < 16; ++i) {
            float4 v = p4[i];
            s4.x += v.x; s4.y += v.y; s4.z += v.z; s4.w += v.w;
        }
        float s = s4.x + s4.y + s4.z + s4.w;
        s += __shfl_xor(s, 1);
        if ((tid & 1) == 0) (ws + OFF_SUMX)[e] = s;
        return;
    }
    __shared__ float wsL[4 * EE];     // 16 KB: the block's 4 W rows
    __shared__ float red[16 * 66];
    int L  = ((const int*)ws)[1];
    int Lp = (L + 63) & ~63;
    int nh = Lp >> 6;                 // 1 or 2 row-halves
    int pid = bid - NRED;             // 0..767
    int m   = pid >> 8;               // 0..2
    int eb  = pid & 255;              // 0..255
    int e0  = eb * 4;
    const float* W = (m == 0) ? Wq : ((m == 1) ? Wk : Wv);
    const float* b = (m == 0) ? bq : ((m == 1) ? bk : bv);

    {   // stage 4 contiguous W rows (16 KB) — coalesced, 4 float4/thread
        const float4* src = (const float4*)(W + (size_t)e0 * EE);
        float4* dst = (float4*)wsL;
#pragma unroll
        for (int i = 0; i < 4; ++i) dst[tid + i * 256] = src[tid + i * 256];
    }
    __syncthreads();

    int lane = tid & 63;
    int w4   = tid >> 6;
    int kbase = w4 * 256;
    const float* x0 = ws + OFF_XT + lane;
    float acc[2][4] = {{0.f, 0.f, 0.f, 0.f}, {0.f, 0.f, 0.f, 0.f}};
    for (int kk = 0; kk < 256; kk += 8) {
        float xv0[8], xv1[8];
#pragma unroll
        for (int u = 0; u < 8; ++u)
            xv0[u] = x0[(size_t)(kbase + kk + u) * RMAX];
        if (nh == 2) {
#pragma unroll
            for (int u = 0; u < 8; ++u)
                xv1[u] = x0[(size_t)(kbase + kk + u) * RMAX + 64];
        }
#pragma unroll
        for (int j = 0; j < 4; ++j) {
            const float4* wp = (const float4*)&wsL[j * EE + kbase + kk];
            float4 wa = wp[0], wb = wp[1];
            acc[0][j] += wa.x * xv0[0] + wa.y * xv0[1] + wa.z * xv0[2] + wa.w * xv0[3]
                       + wb.x * xv0[4] + wb.y * xv0[5] + wb.z * xv0[6] + wb.w * xv0[7];
            if (nh == 2)
                acc[1][j] += wa.x * xv1[0] + wa.y * xv1[1] + wa.z * xv1[2] + wa.w * xv1[3]
                           + wb.x * xv1[4] + wb.y * xv1[5] + wb.z * xv1[6] + wb.w * xv1[7];
        }
    }

    float* qh  = ws + OFF_QH;
    float* kTh = ws + OFF_KTH;
    float* vh  = ws + OFF_VH;
    int h = e0 >> 6;
    for (int h2 = 0; h2 < nh; ++h2) {
        __syncthreads();
#pragma unroll
        for (int j = 0; j < 4; ++j)
            red[(w4 * 4 + j) * 66 + lane] = acc[h2][j];
        __syncthreads();
        int p  = w4;                  // wave -> e index
        int rg = h2 * 64 + lane;
        float v = 0.f;
        if (rg < L)
            v = red[(0 * 4 + p) * 66 + lane] + red[(1 * 4 + p) * 66 + lane]
              + red[(2 * 4 + p) * 66 + lane] + red[(3 * 4 + p) * 66 + lane]
              + b[e0 + p];
        int d0 = (e0 & 63) + p;
        if (m == 1) kTh[(size_t)(h * DD + d0) * RMAX + rg] = v;
        else        ((m == 0) ? qh : vh)[((size_t)h * RMAX + rg) * DD + d0] = v;
    }
}

// -------- D2: bgA (64) || vsumh (16) || attention, 1 wave per (r,h) (256) ----
__global__ __launch_bounds__(256) void d2_kernel(
    const float* __restrict__ Wv, const float* __restrict__ bv,
    float* __restrict__ ws) {
    __shared__ float qS[4 * 64];
    __shared__ float wS[4 * 128];
    __shared__ float vp_[4][64];
    const float* sumx = ws + OFF_SUMX;
    float* bgA    = ws + OFF_BGA;
    float* betap  = ws + OFF_BETA;
    float* alphap = ws + OFF_ALPHA;
    float* vsumh  = ws + OFF_VSUM;
    const float* qh  = ws + OFF_QH;
    const float* kTh = ws + OFF_KTH;
    const float* vh  = ws + OFF_VH;

    int bid = blockIdx.x, tid = threadIdx.x;
    int lane = tid & 63, wave = tid >> 6;
    int L  = ((const int*)ws)[1];
    int Lp = (L + 63) & ~63;

    if (bid < NBG) {
        int e = bid * 16 + (tid >> 4);
        int j = tid & 15;
        const float4* wr  = (const float4*)(Wv + (size_t)e * EE);
        const float4* sx4 = (const float4*)sumx;
        float p = 0.f;
#pragma unroll
        for (int jj = 0; jj < 16; ++jj) {
            float4 w = wr[jj * 16 + j], z = sx4[jj * 16 + j];
            p += w.x * z.x + w.y * z.y + w.z * z.z + w.w * z.w;
        }
        p += __shfl_xor(p, 8);
        p += __shfl_xor(p, 4);
        p += __shfl_xor(p, 2);
        p += __shfl_xor(p, 1);
        if (j == 0) bgA[e] = p + (float)SS * bv[e];
        return;
    }
    if (bid < NBG + NVS) {
        int h = bid - NBG;
        float s = 0.f;
        for (int t = wave; t < Lp; t += 4)
            s += vh[((size_t)h * RMAX + t) * DD + lane];
        vp_[wave][lane] = s;
        __syncthreads();
        if (wave == 0)
            vsumh[h * DD + lane] = vp_[0][lane] + vp_[1][lane]
                                 + vp_[2][lane] + vp_[3][lane];
        return;
    }

    // attention: wave wg handles (r = wg>>4, h = wg&15)
    int aid = bid - NBG - NVS;
    int gidbase = aid * 4 + wave;
    int pairs = L * HH;
    float* qSw = qS + wave * 64;
    float* wSw = wS + wave * 128;
    for (int wg = gidbase; wg < pairs; wg += NATT * 4) {
        int h = wg & (HH - 1);
        int r = wg >> 4;
        qSw[lane] = qh[((size_t)h * RMAX + r) * DD + lane];
        float s0 = 0.f, s1 = 0.f;
#pragma unroll
        for (int d = 0; d < 64; ++d) {
            float qd = qSw[d];
            const float* kr = kTh + (size_t)(h * DD + d) * RMAX;
            s0 += qd * kr[lane];
            s1 += qd * kr[64 + lane];
        }
        float v0 = (lane < L)      ? s0 : -3.0e38f;
        float v1 = (64 + lane < L) ? s1 : -3.0e38f;
        float m = fmaxf(0.f, fmaxf(v0, v1));
#pragma unroll
        for (int off = 32; off; off >>= 1) m = fmaxf(m, __shfl_xor(m, off));
        float w0 = (lane < L)      ? __expf(s0 - m) : 0.f;
        float w1 = (64 + lane < L) ? __expf(s1 - m) : 0.f;
        float Zl = w0 + w1;
#pragma unroll
        for (int off = 32; off; off >>= 1) Zl += __shfl_xor(Zl, off);
        float em = __expf(-m);
        float Z  = Zl + (float)(SS - L) * em;
        wSw[lane]      = w0;
        wSw[64 + lane] = w1;
        float acc = 0.f;
#pragma unroll 16
        for (int t = 0; t < Lp; ++t)
            acc += wSw[t] * vh[((size_t)h * RMAX + t) * DD + lane];
        float invZ = 1.0f / Z;
        atomicAdd(&betap[h * DD + lane], acc * invZ);
        if (lane == 0) atomicAdd(&alphap[h], em * invZ);
    }
}

// -------- D3: out[e] = bo[e] + Wo[e,:].(beta + alpha o (bgA - vsumh)) / L ----
__global__ __launch_bounds__(256) void d3_kernel(
    const float* __restrict__ Wo, const float* __restrict__ bo,
    const float* __restrict__ ws, float* __restrict__ out) {
    __shared__ float z[EE];
    int tid = threadIdx.x;
    int lane = tid & 63, wave = tid >> 6;
    int L = ((const int*)ws)[1];

    {
        int h = tid >> 4;
        float4 beta = ((const float4*)(ws + OFF_BETA))[tid];
        float  a    = (ws + OFF_ALPHA)[h];
        float4 g    = ((const float4*)(ws + OFF_BGA))[tid];
        float4 vs   = ((const float4*)(ws + OFF_VSUM))[tid];
        ((float4*)z)[tid] = make_float4(beta.x + a * (g.x - vs.x),
                                        beta.y + a * (g.y - vs.y),
                                        beta.z + a * (g.z - vs.z),
                                        beta.w + a * (g.w - vs.w));
    }
    __syncthreads();

    int e = blockIdx.x * 4 + wave;
    const float4* wr = (const float4*)(Wo + (size_t)e * EE);
    const float4* z4 = (const float4*)z;
    float p = 0.f;
#pragma unroll
    for (int it = 0; it < 4; ++it) {
        float4 w = wr[it * 64 + lane], zz = z4[it * 64 + lane];
        p += w.x * zz.x + w.y * zz.y + w.z * zz.z + w.w * zz.w;
    }
#pragma unroll
    for (int off = 32; off; off >>= 1) p += __shfl_xor(p, off);
    if (lane == 0) out[e] = bo[e] + p / (float)L;
}

extern "C" void kernel_launch(void* const* d_in, const int* in_sizes, int n_in,
                              void* d_out, int out_size, void* d_ws, size_t ws_size,
                              hipStream_t stream) {
    const float* x   = (const float*)d_in[0];
    const float* Wq  = (const float*)d_in[1];
    const float* bq  = (const float*)d_in[2];
    const float* Wk  = (const float*)d_in[3];
    const float* bk  = (const float*)d_in[4];
    const float* Wv  = (const float*)d_in[5];
    const float* bv  = (const float*)d_in[6];
    const float* Wo  = (const float*)d_in[7];
    const float* bo  = (const float*)d_in[8];
    const int*   seg = (const int*)d_in[9];
    const int*   pos = (const int*)d_in[10];
    float*       out = (float*)d_out;
    float*       ws  = (float*)d_ws;

    d0_kernel<<<NCOL + NTR, 256, 0, stream>>>(x, seg, pos, ws);
    d1_kernel<<<NRED + NPROJ, 256, 0, stream>>>(Wq, bq, Wk, bk, Wv, bv, ws);
    d2_kernel<<<NBG + NVS + NATT, 256, 0, stream>>>(Wv, bv, ws);
    d3_kernel<<<EE / 4, 256, 0, stream>>>(Wo, bo, ws, out);
}